// Round 4
// baseline (455.134 us; speedup 1.0000x reference)
//
#include <hip/hip_runtime.h>
#include <math.h>

// ChunkedSurpriseGatedSSD on MI355X — round 4:
//  - k_gram fused with errgrid: split-bf16 MFMA Grams (fp32-accurate), M kept
//    in LDS (no HBM round-trip), quadform on a 32-point ds grid.
//  - Ms uses an XOR-(t>>2) float4-granule swizzle to kill the 8-way bank
//    conflict that row-aligned float4 layouts force (stride*4 == 0 mod 16).
//  - k_scan: depth-2 prefetch, 512 blocks x 128 threads for 2x MLP.
//
// Identity: h_prev - decay_prev*h_before == h_contrib(c-1) =>
// err(c) = u^T M u / (N*P), M = (B B^T) o (X X^T) (decay-independent),
// u_t = exp(ds*(S63-S_t)). Gate chain walked by one wave over the ds-grid
// (cubic interp).

#define CSZ 64
#define NCH 64
#define NHD 16
#define PD  64
#define ND  128
#define BHN 32
#define NTILES 2048
#define GGRID 32
#define SEQ 4096

// ws layout in floats
#define WS_S   0                  // S cumsum: [tile][t]  (131072)
#define WS_EG  131072             // err_grid: [c][g][bh] (65536)
#define WS_DS  262144             // ds[c] (64)
#define WS_HC  262400             // h_contrib -> h_prev: [tile][n][p] (16777216)

using bf16x8 = __attribute__((ext_vector_type(8))) short;
using f32x4  = __attribute__((ext_vector_type(4))) float;

__device__ __forceinline__ float dot4(float4 a, float4 b) {
  return a.x*b.x + a.y*b.y + a.z*b.z + a.w*b.w;
}
__device__ __forceinline__ short f2bf(float f) {
  union { float f; unsigned u; } v; v.f = f;
  unsigned r = (v.u + 0x7FFFu + ((v.u >> 16) & 1u)) >> 16;
  return (short)r;
}
__device__ __forceinline__ float bf2f(short s) {
  union { float f; unsigned u; } v; v.u = ((unsigned)(unsigned short)s) << 16;
  return v.f;
}

// ---------------- K1: cumsum S + split-bf16 MFMA Grams + err grid (fused) ----
__global__ __launch_bounds__(256, 2) void k_gram(
    const float* __restrict__ X, const float* __restrict__ A,
    const float* __restrict__ Bm, float* __restrict__ ws)
{
  __shared__ short Bhi[64*136], Blo[64*136];   // B[t][n] hi/lo
  __shared__ short Xhi[64*72],  Xlo[64*72];    // X[t][p] hi/lo
  __shared__ float Ms[64*72];                  // M, float4-granule XOR swizzle
  __shared__ float Us[GGRID*68];               // u_g[t]
  __shared__ float Sl[CSZ], Zl[CSZ];

  const int tile = blockIdx.x;
  const int c  = tile & 63;
  const int bh = tile >> 6;
  const int b = bh >> 4, h = bh & 15;
  const int tid = threadIdx.x;

  if (tid < CSZ) Sl[tid] = A[(size_t)(b*SEQ + c*CSZ + tid)*NHD + h];
  __syncthreads();
  if (tid == 0) {
    float acc = 0.f;
    #pragma unroll 1
    for (int t = 0; t < CSZ; ++t) { acc += Sl[t]; Sl[t] = acc; }
  }
  __syncthreads();
  if (tid < CSZ) {
    ws[WS_S + tile*CSZ + tid] = Sl[tid];
    Zl[tid] = Sl[CSZ-1] - Sl[tid];
  }

  {
    const float* Bbase = Bm + ((size_t)(b*SEQ + c*CSZ)*NHD + h)*ND;
    #pragma unroll
    for (int qq = 0; qq < 8; ++qq) {
      int lin = qq*256 + tid;
      int t = lin >> 5, n4 = (lin & 31)*4;
      float4 bv = *(const float4*)(Bbase + (size_t)t*(NHD*ND) + n4);
      short4 h4s, l4s;
      h4s.x = f2bf(bv.x); l4s.x = f2bf(bv.x - bf2f(h4s.x));
      h4s.y = f2bf(bv.y); l4s.y = f2bf(bv.y - bf2f(h4s.y));
      h4s.z = f2bf(bv.z); l4s.z = f2bf(bv.z - bf2f(h4s.z));
      h4s.w = f2bf(bv.w); l4s.w = f2bf(bv.w - bf2f(h4s.w));
      *(short4*)&Bhi[t*136 + n4] = h4s;
      *(short4*)&Blo[t*136 + n4] = l4s;
    }
    const float* Xbase = X + ((size_t)(b*SEQ + c*CSZ)*NHD + h)*PD;
    #pragma unroll
    for (int qq = 0; qq < 4; ++qq) {
      int lin = qq*256 + tid;
      int t = lin >> 4, p4 = (lin & 15)*4;
      float4 xv = *(const float4*)(Xbase + (size_t)t*(NHD*PD) + p4);
      short4 h4s, l4s;
      h4s.x = f2bf(xv.x); l4s.x = f2bf(xv.x - bf2f(h4s.x));
      h4s.y = f2bf(xv.y); l4s.y = f2bf(xv.y - bf2f(h4s.y));
      h4s.z = f2bf(xv.z); l4s.z = f2bf(xv.z - bf2f(h4s.z));
      h4s.w = f2bf(xv.w); l4s.w = f2bf(xv.w - bf2f(h4s.w));
      *(short4*)&Xhi[t*72 + p4] = h4s;
      *(short4*)&Xlo[t*72 + p4] = l4s;
    }
  }
  __syncthreads();

  const int w = tid >> 6;
  const int lane = tid & 63;
  const int m = lane & 15, q = lane >> 4;

  // G_B = B B^T (rows of B as both operands): split-bf16, 3 MFMA per term
  f32x4 gB0 = {0.f,0.f,0.f,0.f}, gB1 = gB0, gB2 = gB0, gB3 = gB0;
  #pragma unroll
  for (int kk = 0; kk < 4; ++kk) {
    bf16x8 ah = *(bf16x8*)&Bhi[(w*16+m)*136 + kk*32 + q*8];
    bf16x8 al = *(bf16x8*)&Blo[(w*16+m)*136 + kk*32 + q*8];
    #pragma unroll
    for (int ct = 0; ct < 4; ++ct) {
      bf16x8 bh_ = *(bf16x8*)&Bhi[(ct*16+m)*136 + kk*32 + q*8];
      bf16x8 bl_ = *(bf16x8*)&Blo[(ct*16+m)*136 + kk*32 + q*8];
      f32x4* g = (ct==0)?&gB0:(ct==1)?&gB1:(ct==2)?&gB2:&gB3;
      *g = __builtin_amdgcn_mfma_f32_16x16x32_bf16(ah, bh_, *g, 0,0,0);
      *g = __builtin_amdgcn_mfma_f32_16x16x32_bf16(ah, bl_, *g, 0,0,0);
      *g = __builtin_amdgcn_mfma_f32_16x16x32_bf16(al, bh_, *g, 0,0,0);
    }
  }
  // G_X = X X^T
  f32x4 gX0 = {0.f,0.f,0.f,0.f}, gX1 = gX0, gX2 = gX0, gX3 = gX0;
  #pragma unroll
  for (int kk = 0; kk < 2; ++kk) {
    bf16x8 ah = *(bf16x8*)&Xhi[(w*16+m)*72 + kk*32 + q*8];
    bf16x8 al = *(bf16x8*)&Xlo[(w*16+m)*72 + kk*32 + q*8];
    #pragma unroll
    for (int ct = 0; ct < 4; ++ct) {
      bf16x8 xh_ = *(bf16x8*)&Xhi[(ct*16+m)*72 + kk*32 + q*8];
      bf16x8 xl_ = *(bf16x8*)&Xlo[(ct*16+m)*72 + kk*32 + q*8];
      f32x4* g = (ct==0)?&gX0:(ct==1)?&gX1:(ct==2)?&gX2:&gX3;
      *g = __builtin_amdgcn_mfma_f32_16x16x32_bf16(ah, xh_, *g, 0,0,0);
      *g = __builtin_amdgcn_mfma_f32_16x16x32_bf16(ah, xl_, *g, 0,0,0);
      *g = __builtin_amdgcn_mfma_f32_16x16x32_bf16(al, xh_, *g, 0,0,0);
    }
  }
  // M = G_B o G_X / (N*P) -> Ms (swizzled). C-layout: row i=w*16+q*4+r, col j=ct*16+m.
  {
    f32x4 gb[4] = {gB0,gB1,gB2,gB3};
    f32x4 gx[4] = {gX0,gX1,gX2,gX3};
    #pragma unroll
    for (int ct = 0; ct < 4; ++ct) {
      int j = ct*16 + m;
      #pragma unroll
      for (int r = 0; r < 4; ++r) {
        int i = w*16 + q*4 + r;
        int s4x = (j >> 2) ^ ((i >> 2) & 7);
        Ms[i*72 + s4x*4 + (j & 3)] = gb[ct][r]*gx[ct][r]*(1.0f/8192.0f);
      }
    }
  }
  // u_g[t] = exp(ds_g * Z_t), ds_g = g/(GGRID-1)
  #pragma unroll
  for (int qq = 0; qq < (GGRID*64)/256; ++qq) {
    int idx = qq*256 + tid;
    int g = idx >> 6, t = idx & 63;
    Us[g*68 + t] = expf(((float)g*(1.0f/(GGRID-1)))*Zl[t]);
  }
  __syncthreads();

  // err_grid[g] = u_g^T M u_g : thread owns g in {g0,g0+1}, t-block t0..t0+3
  {
    const int g0 = (tid >> 4)*2, t0 = (tid & 15)*4;
    const int krow = (t0 >> 2) & 7;   // (t>>2)&7 for all 4 rows of this block
    float wacc[2][4] = {};
    for (int s = 0; s < CSZ; s += 4) {
      int s4x = ((s >> 2) ^ krow) << 2;
      float4 uv0 = *(float4*)&Us[(g0+0)*68 + s];
      float4 uv1 = *(float4*)&Us[(g0+1)*68 + s];
      float4 mv[4];
      #pragma unroll
      for (int qq = 0; qq < 4; ++qq) mv[qq] = *(float4*)&Ms[(t0+qq)*72 + s4x];
      #pragma unroll
      for (int qq = 0; qq < 4; ++qq) {
        wacc[0][qq] += dot4(uv0, mv[qq]);
        wacc[1][qq] += dot4(uv1, mv[qq]);
      }
    }
    #pragma unroll
    for (int r = 0; r < 2; ++r) {
      const float* ur = &Us[(g0+r)*68];
      float e = wacc[r][0]*ur[t0+0] + wacc[r][1]*ur[t0+1]
              + wacc[r][2]*ur[t0+2] + wacc[r][3]*ur[t0+3];
      e += __shfl_xor(e, 1);
      e += __shfl_xor(e, 2);
      e += __shfl_xor(e, 4);
      e += __shfl_xor(e, 8);
      if ((tid & 15) == 0) ws[WS_EG + (c*GGRID + g0 + r)*BHN + bh] = e;
    }
  }
}

// ---------------- K2: sequential gate chain (one wave) ----------------
__global__ __launch_bounds__(64) void k_gate(
    const float* __restrict__ l2ab, const float* __restrict__ l2b,
    const float* __restrict__ sema, float* __restrict__ ws)
{
  const int lane = threadIdx.x;
  const int h = lane & 15;
  float ab = 0.f, bt = 1.f, ema = 0.f;
  if (lane < NHD) {
    float la = fminf(fmaxf(l2ab[lane], -3.32f), -0.015f);
    ab = 1.0f - exp2f(la);
    float lb = fminf(fmaxf(l2b[lane], -2.0f), 2.0f);
    bt = exp2f(lb);
    ema = sema[lane];
  }
  const float ab_bh = __shfl(ab, h);
  const float bt_bh = __shfl(bt, h);
  float ds_prev = 1.0f;
  if (lane == 0) ws[WS_DS + 0] = 1.0f;
  const float* EG = ws + WS_EG;
  for (int c = 1; c < NCH; ++c) {
    const int j = c - 1;
    float x = ds_prev * (float)(GGRID-1);
    int ib = (int)floorf(x);
    ib = max(1, min(GGRID-3, ib));
    float u = x - (float)ib;
    float err = 0.f;
    if (lane < BHN) {
      const float* p = EG + ((size_t)j*GGRID + (ib-1))*BHN + lane;
      float ym1 = p[0], y0 = p[BHN], y1 = p[2*BHN], y2 = p[3*BHN];
      err = ym1*(u*(u-1.f)*(u-2.f))*(-1.f/6.f)
          + y0 *((u+1.f)*(u-1.f)*(u-2.f))*(0.5f)
          + y1 *((u+1.f)*u*(u-2.f))*(-0.5f)
          + y2 *((u+1.f)*u*(u-1.f))*(1.f/6.f);
    }
    float e0 = __shfl(err, h);
    float e1 = __shfl(err, 16 + h);
    float ema_new = 0.99f*ema + 0.01f*0.5f*(e0 + e1);
    float emv = __shfl(ema_new, h);
    float oma = 0.f;
    if (lane < BHN) {
      float normalized = err / (emv + 1e-6f);
      float boost = fmaxf(tanhf(bt_bh*normalized), 0.f);
      float alpha = ab_bh + (1.f - ab_bh)*boost;
      alpha = fminf(fmaxf(alpha, 0.01f), 0.999f);
      oma = 1.f - alpha;
    }
    float s = oma;
    s += __shfl_xor(s, 1);  s += __shfl_xor(s, 2);  s += __shfl_xor(s, 4);
    s += __shfl_xor(s, 8);  s += __shfl_xor(s, 16);
    float ds = __shfl(s, 0) * (1.0f/32.0f);
    if (lane < NHD) ema = ema_new;
    if (lane == 0) ws[WS_DS + c] = ds;
    ds_prev = ds;
  }
}

// ---------------- K3: MFMA — CB, Y_intra, h_contrib ----------------
__global__ __launch_bounds__(256, 2) void k_chunk(
    const float* __restrict__ X, const float* __restrict__ Bm,
    const float* __restrict__ Cm, float* __restrict__ ws,
    float* __restrict__ Y)
{
  __shared__ short Cs[64*136];
  __shared__ short Bs[64*136];
  __shared__ short BsTw[128*72];
  __shared__ short XsT[64*72];
  __shared__ short Es[64*72];
  __shared__ float Acs[CSZ];
  __shared__ float Wl[CSZ];

  const int tile = blockIdx.x;
  const int c  = tile & 63;
  const int bh = tile >> 6;
  const int b = bh >> 4, h = bh & 15;
  const int tid = threadIdx.x;

  const float dsc = ws[WS_DS + c];
  if (tid < CSZ) {
    float sv  = ws[WS_S + tile*CSZ + tid];
    float s63 = ws[WS_S + tile*CSZ + 63];
    Acs[tid] = dsc*sv;
    Wl[tid]  = expf(dsc*(s63 - sv));
  }
  __syncthreads();

  const float* Bbase = Bm + ((size_t)(b*SEQ + c*CSZ)*NHD + h)*ND;
  const float* Cbase = Cm + ((size_t)(b*SEQ + c*CSZ)*NHD + h)*ND;
  const float* Xbase = X  + ((size_t)(b*SEQ + c*CSZ)*NHD + h)*PD;
  #pragma unroll
  for (int qq = 0; qq < 8; ++qq) {
    int lin = qq*256 + tid;
    int t = lin >> 5, n4 = (lin & 31)*4;
    float4 cv = *(const float4*)(Cbase + (size_t)t*(NHD*ND) + n4);
    short4 cs4; cs4.x=f2bf(cv.x); cs4.y=f2bf(cv.y); cs4.z=f2bf(cv.z); cs4.w=f2bf(cv.w);
    *(short4*)&Cs[t*136 + n4] = cs4;
    float4 bv = *(const float4*)(Bbase + (size_t)t*(NHD*ND) + n4);
    short4 bs4; bs4.x=f2bf(bv.x); bs4.y=f2bf(bv.y); bs4.z=f2bf(bv.z); bs4.w=f2bf(bv.w);
    *(short4*)&Bs[t*136 + n4] = bs4;
    float wt = Wl[t];
    BsTw[(n4+0)*72 + t] = f2bf(bv.x*wt);
    BsTw[(n4+1)*72 + t] = f2bf(bv.y*wt);
    BsTw[(n4+2)*72 + t] = f2bf(bv.z*wt);
    BsTw[(n4+3)*72 + t] = f2bf(bv.w*wt);
  }
  #pragma unroll
  for (int qq = 0; qq < 4; ++qq) {
    int lin = qq*256 + tid;
    int t = lin >> 4, p4 = (lin & 15)*4;
    float4 xv = *(const float4*)(Xbase + (size_t)t*(NHD*PD) + p4);
    XsT[(p4+0)*72 + t] = f2bf(xv.x);
    XsT[(p4+1)*72 + t] = f2bf(xv.y);
    XsT[(p4+2)*72 + t] = f2bf(xv.z);
    XsT[(p4+3)*72 + t] = f2bf(xv.w);
  }
  __syncthreads();

  const int w = tid >> 6;
  const int lane = tid & 63;
  const int m = lane & 15, q = lane >> 4;

  // GEMM1: CB[i][j]
  f32x4 acc0 = {0.f,0.f,0.f,0.f}, acc1 = acc0, acc2 = acc0, acc3 = acc0;
  #pragma unroll
  for (int kk = 0; kk < 4; ++kk) {
    bf16x8 af = *(bf16x8*)&Cs[(w*16+m)*136 + kk*32 + q*8];
    bf16x8 b0 = *(bf16x8*)&Bs[( 0+m)*136 + kk*32 + q*8];
    bf16x8 b1 = *(bf16x8*)&Bs[(16+m)*136 + kk*32 + q*8];
    bf16x8 b2 = *(bf16x8*)&Bs[(32+m)*136 + kk*32 + q*8];
    bf16x8 b3 = *(bf16x8*)&Bs[(48+m)*136 + kk*32 + q*8];
    acc0 = __builtin_amdgcn_mfma_f32_16x16x32_bf16(af, b0, acc0, 0,0,0);
    acc1 = __builtin_amdgcn_mfma_f32_16x16x32_bf16(af, b1, acc1, 0,0,0);
    acc2 = __builtin_amdgcn_mfma_f32_16x16x32_bf16(af, b2, acc2, 0,0,0);
    acc3 = __builtin_amdgcn_mfma_f32_16x16x32_bf16(af, b3, acc3, 0,0,0);
  }
  {
    f32x4 accs[4] = {acc0, acc1, acc2, acc3};
    #pragma unroll
    for (int ct = 0; ct < 4; ++ct) {
      int j = ct*16 + m;
      float aj = Acs[j];
      #pragma unroll
      for (int r = 0; r < 4; ++r) {
        int i = w*16 + q*4 + r;
        float v = (i >= j) ? expf(Acs[i]-aj)*accs[ct][r] : 0.f;
        Es[i*72 + j] = f2bf(v);
      }
    }
  }

  // GEMM3: h_contrib[n][p]
  f32x4 h00={0.f,0.f,0.f,0.f}, h01=h00, h02=h00, h03=h00;
  f32x4 h10=h00, h11=h00, h12=h00, h13=h00;
  #pragma unroll
  for (int kk = 0; kk < 2; ++kk) {
    bf16x8 a0 = *(bf16x8*)&BsTw[((2*w+0)*16+m)*72 + kk*32 + q*8];
    bf16x8 a1 = *(bf16x8*)&BsTw[((2*w+1)*16+m)*72 + kk*32 + q*8];
    bf16x8 x0 = *(bf16x8*)&XsT[( 0+m)*72 + kk*32 + q*8];
    bf16x8 x1 = *(bf16x8*)&XsT[(16+m)*72 + kk*32 + q*8];
    bf16x8 x2 = *(bf16x8*)&XsT[(32+m)*72 + kk*32 + q*8];
    bf16x8 x3 = *(bf16x8*)&XsT[(48+m)*72 + kk*32 + q*8];
    h00 = __builtin_amdgcn_mfma_f32_16x16x32_bf16(a0, x0, h00, 0,0,0);
    h01 = __builtin_amdgcn_mfma_f32_16x16x32_bf16(a0, x1, h01, 0,0,0);
    h02 = __builtin_amdgcn_mfma_f32_16x16x32_bf16(a0, x2, h02, 0,0,0);
    h03 = __builtin_amdgcn_mfma_f32_16x16x32_bf16(a0, x3, h03, 0,0,0);
    h10 = __builtin_amdgcn_mfma_f32_16x16x32_bf16(a1, x0, h10, 0,0,0);
    h11 = __builtin_amdgcn_mfma_f32_16x16x32_bf16(a1, x1, h11, 0,0,0);
    h12 = __builtin_amdgcn_mfma_f32_16x16x32_bf16(a1, x2, h12, 0,0,0);
    h13 = __builtin_amdgcn_mfma_f32_16x16x32_bf16(a1, x3, h13, 0,0,0);
  }

  // GEMM2: Y_intra = E @ X (Es rows written by this wave)
  f32x4 y0={0.f,0.f,0.f,0.f}, y1=y0, y2=y0, y3=y0;
  #pragma unroll
  for (int kk = 0; kk < 2; ++kk) {
    bf16x8 ef = *(bf16x8*)&Es[(w*16+m)*72 + kk*32 + q*8];
    bf16x8 x0 = *(bf16x8*)&XsT[( 0+m)*72 + kk*32 + q*8];
    bf16x8 x1 = *(bf16x8*)&XsT[(16+m)*72 + kk*32 + q*8];
    bf16x8 x2 = *(bf16x8*)&XsT[(32+m)*72 + kk*32 + q*8];
    bf16x8 x3 = *(bf16x8*)&XsT[(48+m)*72 + kk*32 + q*8];
    y0 = __builtin_amdgcn_mfma_f32_16x16x32_bf16(ef, x0, y0, 0,0,0);
    y1 = __builtin_amdgcn_mfma_f32_16x16x32_bf16(ef, x1, y1, 0,0,0);
    y2 = __builtin_amdgcn_mfma_f32_16x16x32_bf16(ef, x2, y2, 0,0,0);
    y3 = __builtin_amdgcn_mfma_f32_16x16x32_bf16(ef, x3, y3, 0,0,0);
  }

  {
    float* Ybase = Y + ((size_t)(b*SEQ + c*CSZ)*NHD + h)*PD;
    f32x4 ys[4] = {y0, y1, y2, y3};
    #pragma unroll
    for (int r = 0; r < 4; ++r) {
      int i = w*16 + q*4 + r;
      #pragma unroll
      for (int ct = 0; ct < 4; ++ct)
        Ybase[(size_t)i*(NHD*PD) + ct*16 + m] = ys[ct][r];
    }
  }
  {
    float* hcp = ws + WS_HC + (size_t)tile*(ND*PD);
    f32x4 hs[2][4] = {{h00,h01,h02,h03},{h10,h11,h12,h13}};
    #pragma unroll
    for (int nt = 0; nt < 2; ++nt)
      #pragma unroll
      for (int r = 0; r < 4; ++r) {
        int n = (2*w+nt)*16 + q*4 + r;
        #pragma unroll
        for (int pt = 0; pt < 4; ++pt)
          hcp[n*PD + pt*16 + m] = hs[nt][pt][r];
      }
  }
}

// ---------------- K4: h-state scan (in place, depth-2 prefetch) -------------
__global__ __launch_bounds__(128) void k_scan(float* __restrict__ ws)
{
  __shared__ float dtbl[NCH];
  const int bh = blockIdx.x >> 4, part = blockIdx.x & 15;
  const int tid = threadIdx.x;
  if (tid < NCH) {
    float s63 = ws[WS_S + (bh*NCH + tid)*CSZ + 63];
    dtbl[tid] = expf(ws[WS_DS + tid]*s63);
  }
  __syncthreads();
  float* base = ws + WS_HC + (size_t)bh*(NCH*ND*PD) + part*512 + tid*4;
  float4 h4 = make_float4(0.f, 0.f, 0.f, 0.f);
  float4 v0 = *(float4*)(base);
  float4 v1 = *(float4*)(base + (size_t)(ND*PD));
  #pragma unroll 1
  for (int c = 0; c < NCH; ++c) {
    float4 vn = make_float4(0.f,0.f,0.f,0.f);
    if (c + 2 < NCH) vn = *(float4*)(base + (size_t)(c+2)*(ND*PD));
    *(float4*)(base + (size_t)c*(ND*PD)) = h4;
    float dt = dtbl[c];
    h4.x = dt*h4.x + v0.x;  h4.y = dt*h4.y + v0.y;
    h4.z = dt*h4.z + v0.z;  h4.w = dt*h4.w + v0.w;
    v0 = v1; v1 = vn;
  }
}

// ---------------- K5: MFMA — Y += dfs o (C @ h_prev) ----------------
__global__ __launch_bounds__(256, 4) void k_inter(
    const float* __restrict__ Cm, float* __restrict__ ws,
    float* __restrict__ Y)
{
  __shared__ short Cs[64*136];
  __shared__ short HsT[64*136];
  __shared__ float Dfs[CSZ];

  const int tile = blockIdx.x;
  const int c  = tile & 63;
  const int bh = tile >> 6;
  const int b = bh >> 4, h = bh & 15;
  const int tid = threadIdx.x;

  const float dsc = ws[WS_DS + c];
  if (tid < CSZ) Dfs[tid] = expf(dsc*ws[WS_S + tile*CSZ + tid]);

  const float* Cbase = Cm + ((size_t)(b*SEQ + c*CSZ)*NHD + h)*ND;
  const float* hp = ws + WS_HC + (size_t)tile*(ND*PD);
  #pragma unroll
  for (int qq = 0; qq < 8; ++qq) {
    int lin = qq*256 + tid;
    int t = lin >> 5, n4 = (lin & 31)*4;
    float4 cv = *(const float4*)(Cbase + (size_t)t*(NHD*ND) + n4);
    short4 cs4; cs4.x=f2bf(cv.x); cs4.y=f2bf(cv.y); cs4.z=f2bf(cv.z); cs4.w=f2bf(cv.w);
    *(short4*)&Cs[t*136 + n4] = cs4;
    int p4 = (lin & 15)*4, n = lin >> 4;
    float4 hv = *(const float4*)(hp + (size_t)lin*4);
    HsT[(p4+0)*136 + n] = f2bf(hv.x);
    HsT[(p4+1)*136 + n] = f2bf(hv.y);
    HsT[(p4+2)*136 + n] = f2bf(hv.z);
    HsT[(p4+3)*136 + n] = f2bf(hv.w);
  }
  __syncthreads();

  const int w = tid >> 6;
  const int lane = tid & 63;
  const int m = lane & 15, q = lane >> 4;

  f32x4 a0 = {0.f,0.f,0.f,0.f}, a1 = a0, a2 = a0, a3 = a0;
  #pragma unroll
  for (int kk = 0; kk < 4; ++kk) {
    bf16x8 cf = *(bf16x8*)&Cs[(w*16+m)*136 + kk*32 + q*8];
    bf16x8 hb0 = *(bf16x8*)&HsT[( 0+m)*136 + kk*32 + q*8];
    bf16x8 hb1 = *(bf16x8*)&HsT[(16+m)*136 + kk*32 + q*8];
    bf16x8 hb2 = *(bf16x8*)&HsT[(32+m)*136 + kk*32 + q*8];
    bf16x8 hb3 = *(bf16x8*)&HsT[(48+m)*136 + kk*32 + q*8];
    a0 = __builtin_amdgcn_mfma_f32_16x16x32_bf16(cf, hb0, a0, 0,0,0);
    a1 = __builtin_amdgcn_mfma_f32_16x16x32_bf16(cf, hb1, a1, 0,0,0);
    a2 = __builtin_amdgcn_mfma_f32_16x16x32_bf16(cf, hb2, a2, 0,0,0);
    a3 = __builtin_amdgcn_mfma_f32_16x16x32_bf16(cf, hb3, a3, 0,0,0);
  }

  float* Ybase = Y + ((size_t)(b*SEQ + c*CSZ)*NHD + h)*PD;
  f32x4 as[4] = {a0, a1, a2, a3};
  #pragma unroll
  for (int r = 0; r < 4; ++r) {
    int i = w*16 + q*4 + r;
    float d = Dfs[i];
    #pragma unroll
    for (int ct = 0; ct < 4; ++ct) {
      size_t idx = (size_t)i*(NHD*PD) + ct*16 + m;
      Ybase[idx] += d*as[ct][r];
    }
  }
}

extern "C" void kernel_launch(void* const* d_in, const int* in_sizes, int n_in,
                              void* d_out, int out_size, void* d_ws, size_t ws_size,
                              hipStream_t stream) {
  const float* X    = (const float*)d_in[0];
  const float* A    = (const float*)d_in[1];
  const float* Bm   = (const float*)d_in[2];
  const float* Cm   = (const float*)d_in[3];
  const float* l2ab = (const float*)d_in[4];
  const float* l2b  = (const float*)d_in[5];
  const float* sema = (const float*)d_in[6];
  float* Y  = (float*)d_out;
  float* ws = (float*)d_ws;

  hipLaunchKernelGGL(k_gram,  dim3(NTILES), dim3(256), 0, stream, X, A, Bm, ws);
  hipLaunchKernelGGL(k_gate,  dim3(1),      dim3(64),  0, stream, l2ab, l2b, sema, ws);
  hipLaunchKernelGGL(k_chunk, dim3(NTILES), dim3(256), 0, stream, X, Bm, Cm, ws, Y);
  hipLaunchKernelGGL(k_scan,  dim3(512),    dim3(128), 0, stream, ws);
  hipLaunchKernelGGL(k_inter, dim3(NTILES), dim3(256), 0, stream, Cm, ws, Y);
}

// Round 5
// 452.873 us; speedup vs baseline: 1.0050x; 1.0050x over previous
//
#include <hip/hip_runtime.h>
#include <math.h>

// ChunkedSurpriseGatedSSD on MI355X — round 5: fix k_gram scratch spill.
// Round 4's `f32x4* g = (ct==0)?&gB0:...` took addresses of MFMA accumulators
// -> compiler demoted them to scratch -> 290 MB of spill traffic (WRITE_SIZE
// 228 MB, MfmaUtil 2.4%). Rewritten with explicitly named accumulators.
//
// Identity: h_prev - decay_prev*h_before == h_contrib(c-1) =>
// err(c) = u^T M u / (N*P), M = (B B^T) o (X X^T) (decay-independent),
// u_t = exp(ds*(S63-S_t)). Gate chain walked by one wave over the ds-grid
// (cubic interp).

#define CSZ 64
#define NCH 64
#define NHD 16
#define PD  64
#define ND  128
#define BHN 32
#define NTILES 2048
#define GGRID 32
#define SEQ 4096

// ws layout in floats
#define WS_S   0                  // S cumsum: [tile][t]  (131072)
#define WS_EG  131072             // err_grid: [c][g][bh] (65536)
#define WS_DS  262144             // ds[c] (64)
#define WS_HC  262400             // h_contrib -> h_prev: [tile][n][p] (16777216)

using bf16x8 = __attribute__((ext_vector_type(8))) short;
using f32x4  = __attribute__((ext_vector_type(4))) float;

__device__ __forceinline__ float dot4(float4 a, float4 b) {
  return a.x*b.x + a.y*b.y + a.z*b.z + a.w*b.w;
}
__device__ __forceinline__ short f2bf(float f) {
  union { float f; unsigned u; } v; v.f = f;
  unsigned r = (v.u + 0x7FFFu + ((v.u >> 16) & 1u)) >> 16;
  return (short)r;
}
__device__ __forceinline__ float bf2f(short s) {
  union { float f; unsigned u; } v; v.u = ((unsigned)(unsigned short)s) << 16;
  return v.f;
}

// ---------------- K1: cumsum S + split-bf16 MFMA Grams + err grid (fused) ----
__global__ __launch_bounds__(256, 2) void k_gram(
    const float* __restrict__ X, const float* __restrict__ A,
    const float* __restrict__ Bm, float* __restrict__ ws)
{
  __shared__ short Bhi[64*136], Blo[64*136];   // B[t][n] hi/lo
  __shared__ short Xhi[64*72],  Xlo[64*72];    // X[t][p] hi/lo
  __shared__ float Ms[64*72];                  // M, float4-granule XOR swizzle
  __shared__ float Us[GGRID*68];               // u_g[t]
  __shared__ float Sl[CSZ], Zl[CSZ];

  const int tile = blockIdx.x;
  const int c  = tile & 63;
  const int bh = tile >> 6;
  const int b = bh >> 4, h = bh & 15;
  const int tid = threadIdx.x;

  if (tid < CSZ) Sl[tid] = A[(size_t)(b*SEQ + c*CSZ + tid)*NHD + h];
  __syncthreads();
  if (tid == 0) {
    float acc = 0.f;
    #pragma unroll 1
    for (int t = 0; t < CSZ; ++t) { acc += Sl[t]; Sl[t] = acc; }
  }
  __syncthreads();
  if (tid < CSZ) {
    ws[WS_S + tile*CSZ + tid] = Sl[tid];
    Zl[tid] = Sl[CSZ-1] - Sl[tid];
  }

  {
    const float* Bbase = Bm + ((size_t)(b*SEQ + c*CSZ)*NHD + h)*ND;
    #pragma unroll
    for (int qq = 0; qq < 8; ++qq) {
      int lin = qq*256 + tid;
      int t = lin >> 5, n4 = (lin & 31)*4;
      float4 bv = *(const float4*)(Bbase + (size_t)t*(NHD*ND) + n4);
      short4 h4s, l4s;
      h4s.x = f2bf(bv.x); l4s.x = f2bf(bv.x - bf2f(h4s.x));
      h4s.y = f2bf(bv.y); l4s.y = f2bf(bv.y - bf2f(h4s.y));
      h4s.z = f2bf(bv.z); l4s.z = f2bf(bv.z - bf2f(h4s.z));
      h4s.w = f2bf(bv.w); l4s.w = f2bf(bv.w - bf2f(h4s.w));
      *(short4*)&Bhi[t*136 + n4] = h4s;
      *(short4*)&Blo[t*136 + n4] = l4s;
    }
    const float* Xbase = X + ((size_t)(b*SEQ + c*CSZ)*NHD + h)*PD;
    #pragma unroll
    for (int qq = 0; qq < 4; ++qq) {
      int lin = qq*256 + tid;
      int t = lin >> 4, p4 = (lin & 15)*4;
      float4 xv = *(const float4*)(Xbase + (size_t)t*(NHD*PD) + p4);
      short4 h4s, l4s;
      h4s.x = f2bf(xv.x); l4s.x = f2bf(xv.x - bf2f(h4s.x));
      h4s.y = f2bf(xv.y); l4s.y = f2bf(xv.y - bf2f(h4s.y));
      h4s.z = f2bf(xv.z); l4s.z = f2bf(xv.z - bf2f(h4s.z));
      h4s.w = f2bf(xv.w); l4s.w = f2bf(xv.w - bf2f(h4s.w));
      *(short4*)&Xhi[t*72 + p4] = h4s;
      *(short4*)&Xlo[t*72 + p4] = l4s;
    }
  }
  __syncthreads();

  const int w = tid >> 6;
  const int lane = tid & 63;
  const int m = lane & 15, q = lane >> 4;

  // G_B = B B^T: split-bf16, 3 MFMA per (kk,ct). NO address-taking.
  f32x4 gB0 = {0.f,0.f,0.f,0.f}, gB1 = gB0, gB2 = gB0, gB3 = gB0;
  #pragma unroll
  for (int kk = 0; kk < 4; ++kk) {
    bf16x8 ah = *(bf16x8*)&Bhi[(w*16+m)*136 + kk*32 + q*8];
    bf16x8 al = *(bf16x8*)&Blo[(w*16+m)*136 + kk*32 + q*8];
    bf16x8 b0h = *(bf16x8*)&Bhi[( 0+m)*136 + kk*32 + q*8];
    bf16x8 b0l = *(bf16x8*)&Blo[( 0+m)*136 + kk*32 + q*8];
    bf16x8 b1h = *(bf16x8*)&Bhi[(16+m)*136 + kk*32 + q*8];
    bf16x8 b1l = *(bf16x8*)&Blo[(16+m)*136 + kk*32 + q*8];
    bf16x8 b2h = *(bf16x8*)&Bhi[(32+m)*136 + kk*32 + q*8];
    bf16x8 b2l = *(bf16x8*)&Blo[(32+m)*136 + kk*32 + q*8];
    bf16x8 b3h = *(bf16x8*)&Bhi[(48+m)*136 + kk*32 + q*8];
    bf16x8 b3l = *(bf16x8*)&Blo[(48+m)*136 + kk*32 + q*8];
    gB0 = __builtin_amdgcn_mfma_f32_16x16x32_bf16(ah, b0h, gB0, 0,0,0);
    gB0 = __builtin_amdgcn_mfma_f32_16x16x32_bf16(ah, b0l, gB0, 0,0,0);
    gB0 = __builtin_amdgcn_mfma_f32_16x16x32_bf16(al, b0h, gB0, 0,0,0);
    gB1 = __builtin_amdgcn_mfma_f32_16x16x32_bf16(ah, b1h, gB1, 0,0,0);
    gB1 = __builtin_amdgcn_mfma_f32_16x16x32_bf16(ah, b1l, gB1, 0,0,0);
    gB1 = __builtin_amdgcn_mfma_f32_16x16x32_bf16(al, b1h, gB1, 0,0,0);
    gB2 = __builtin_amdgcn_mfma_f32_16x16x32_bf16(ah, b2h, gB2, 0,0,0);
    gB2 = __builtin_amdgcn_mfma_f32_16x16x32_bf16(ah, b2l, gB2, 0,0,0);
    gB2 = __builtin_amdgcn_mfma_f32_16x16x32_bf16(al, b2h, gB2, 0,0,0);
    gB3 = __builtin_amdgcn_mfma_f32_16x16x32_bf16(ah, b3h, gB3, 0,0,0);
    gB3 = __builtin_amdgcn_mfma_f32_16x16x32_bf16(ah, b3l, gB3, 0,0,0);
    gB3 = __builtin_amdgcn_mfma_f32_16x16x32_bf16(al, b3h, gB3, 0,0,0);
  }
  // G_X = X X^T
  f32x4 gX0 = {0.f,0.f,0.f,0.f}, gX1 = gX0, gX2 = gX0, gX3 = gX0;
  #pragma unroll
  for (int kk = 0; kk < 2; ++kk) {
    bf16x8 ah = *(bf16x8*)&Xhi[(w*16+m)*72 + kk*32 + q*8];
    bf16x8 al = *(bf16x8*)&Xlo[(w*16+m)*72 + kk*32 + q*8];
    bf16x8 x0h = *(bf16x8*)&Xhi[( 0+m)*72 + kk*32 + q*8];
    bf16x8 x0l = *(bf16x8*)&Xlo[( 0+m)*72 + kk*32 + q*8];
    bf16x8 x1h = *(bf16x8*)&Xhi[(16+m)*72 + kk*32 + q*8];
    bf16x8 x1l = *(bf16x8*)&Xlo[(16+m)*72 + kk*32 + q*8];
    bf16x8 x2h = *(bf16x8*)&Xhi[(32+m)*72 + kk*32 + q*8];
    bf16x8 x2l = *(bf16x8*)&Xlo[(32+m)*72 + kk*32 + q*8];
    bf16x8 x3h = *(bf16x8*)&Xhi[(48+m)*72 + kk*32 + q*8];
    bf16x8 x3l = *(bf16x8*)&Xlo[(48+m)*72 + kk*32 + q*8];
    gX0 = __builtin_amdgcn_mfma_f32_16x16x32_bf16(ah, x0h, gX0, 0,0,0);
    gX0 = __builtin_amdgcn_mfma_f32_16x16x32_bf16(ah, x0l, gX0, 0,0,0);
    gX0 = __builtin_amdgcn_mfma_f32_16x16x32_bf16(al, x0h, gX0, 0,0,0);
    gX1 = __builtin_amdgcn_mfma_f32_16x16x32_bf16(ah, x1h, gX1, 0,0,0);
    gX1 = __builtin_amdgcn_mfma_f32_16x16x32_bf16(ah, x1l, gX1, 0,0,0);
    gX1 = __builtin_amdgcn_mfma_f32_16x16x32_bf16(al, x1h, gX1, 0,0,0);
    gX2 = __builtin_amdgcn_mfma_f32_16x16x32_bf16(ah, x2h, gX2, 0,0,0);
    gX2 = __builtin_amdgcn_mfma_f32_16x16x32_bf16(ah, x2l, gX2, 0,0,0);
    gX2 = __builtin_amdgcn_mfma_f32_16x16x32_bf16(al, x2h, gX2, 0,0,0);
    gX3 = __builtin_amdgcn_mfma_f32_16x16x32_bf16(ah, x3h, gX3, 0,0,0);
    gX3 = __builtin_amdgcn_mfma_f32_16x16x32_bf16(ah, x3l, gX3, 0,0,0);
    gX3 = __builtin_amdgcn_mfma_f32_16x16x32_bf16(al, x3h, gX3, 0,0,0);
  }
  // M = G_B o G_X / (N*P) -> Ms (swizzled). C-layout: row i=w*16+q*4+r, col j=ct*16+m.
  {
    #pragma unroll
    for (int r = 0; r < 4; ++r) {
      int i = w*16 + q*4 + r;
      int j0c = 0*16 + m;
      int s4x0 = ((j0c >> 2) ^ ((i >> 2) & 7));
      Ms[i*72 + s4x0*4 + (j0c & 3)] = gB0[r]*gX0[r]*(1.0f/8192.0f);
      int j1c = 1*16 + m;
      int s4x1 = ((j1c >> 2) ^ ((i >> 2) & 7));
      Ms[i*72 + s4x1*4 + (j1c & 3)] = gB1[r]*gX1[r]*(1.0f/8192.0f);
      int j2c = 2*16 + m;
      int s4x2 = ((j2c >> 2) ^ ((i >> 2) & 7));
      Ms[i*72 + s4x2*4 + (j2c & 3)] = gB2[r]*gX2[r]*(1.0f/8192.0f);
      int j3c = 3*16 + m;
      int s4x3 = ((j3c >> 2) ^ ((i >> 2) & 7));
      Ms[i*72 + s4x3*4 + (j3c & 3)] = gB3[r]*gX3[r]*(1.0f/8192.0f);
    }
  }
  // u_g[t] = exp(ds_g * Z_t), ds_g = g/(GGRID-1)
  #pragma unroll
  for (int qq = 0; qq < (GGRID*64)/256; ++qq) {
    int idx = qq*256 + tid;
    int g = idx >> 6, t = idx & 63;
    Us[g*68 + t] = expf(((float)g*(1.0f/(GGRID-1)))*Zl[t]);
  }
  __syncthreads();

  // err_grid[g] = u_g^T M u_g : thread owns g in {g0,g0+1}, t-block t0..t0+3
  {
    const int g0 = (tid >> 4)*2, t0 = (tid & 15)*4;
    const int krow = (t0 >> 2) & 7;
    float wacc[2][4] = {};
    for (int s = 0; s < CSZ; s += 4) {
      int s4x = ((s >> 2) ^ krow) << 2;
      float4 uv0 = *(float4*)&Us[(g0+0)*68 + s];
      float4 uv1 = *(float4*)&Us[(g0+1)*68 + s];
      float4 mv[4];
      #pragma unroll
      for (int qq = 0; qq < 4; ++qq) mv[qq] = *(float4*)&Ms[(t0+qq)*72 + s4x];
      #pragma unroll
      for (int qq = 0; qq < 4; ++qq) {
        wacc[0][qq] += dot4(uv0, mv[qq]);
        wacc[1][qq] += dot4(uv1, mv[qq]);
      }
    }
    #pragma unroll
    for (int r = 0; r < 2; ++r) {
      const float* ur = &Us[(g0+r)*68];
      float e = wacc[r][0]*ur[t0+0] + wacc[r][1]*ur[t0+1]
              + wacc[r][2]*ur[t0+2] + wacc[r][3]*ur[t0+3];
      e += __shfl_xor(e, 1);
      e += __shfl_xor(e, 2);
      e += __shfl_xor(e, 4);
      e += __shfl_xor(e, 8);
      if ((tid & 15) == 0) ws[WS_EG + (c*GGRID + g0 + r)*BHN + bh] = e;
    }
  }
}

// ---------------- K2: sequential gate chain (one wave) ----------------
__global__ __launch_bounds__(64) void k_gate(
    const float* __restrict__ l2ab, const float* __restrict__ l2b,
    const float* __restrict__ sema, float* __restrict__ ws)
{
  const int lane = threadIdx.x;
  const int h = lane & 15;
  float ab = 0.f, bt = 1.f, ema = 0.f;
  if (lane < NHD) {
    float la = fminf(fmaxf(l2ab[lane], -3.32f), -0.015f);
    ab = 1.0f - exp2f(la);
    float lb = fminf(fmaxf(l2b[lane], -2.0f), 2.0f);
    bt = exp2f(lb);
    ema = sema[lane];
  }
  const float ab_bh = __shfl(ab, h);
  const float bt_bh = __shfl(bt, h);
  float ds_prev = 1.0f;
  if (lane == 0) ws[WS_DS + 0] = 1.0f;
  const float* EG = ws + WS_EG;
  for (int c = 1; c < NCH; ++c) {
    const int j = c - 1;
    float x = ds_prev * (float)(GGRID-1);
    int ib = (int)floorf(x);
    ib = max(1, min(GGRID-3, ib));
    float u = x - (float)ib;
    float err = 0.f;
    if (lane < BHN) {
      const float* p = EG + ((size_t)j*GGRID + (ib-1))*BHN + lane;
      float ym1 = p[0], y0 = p[BHN], y1 = p[2*BHN], y2 = p[3*BHN];
      err = ym1*(u*(u-1.f)*(u-2.f))*(-1.f/6.f)
          + y0 *((u+1.f)*(u-1.f)*(u-2.f))*(0.5f)
          + y1 *((u+1.f)*u*(u-2.f))*(-0.5f)
          + y2 *((u+1.f)*u*(u-1.f))*(1.f/6.f);
    }
    float e0 = __shfl(err, h);
    float e1 = __shfl(err, 16 + h);
    float ema_new = 0.99f*ema + 0.01f*0.5f*(e0 + e1);
    float emv = __shfl(ema_new, h);
    float oma = 0.f;
    if (lane < BHN) {
      float normalized = err / (emv + 1e-6f);
      float boost = fmaxf(tanhf(bt_bh*normalized), 0.f);
      float alpha = ab_bh + (1.f - ab_bh)*boost;
      alpha = fminf(fmaxf(alpha, 0.01f), 0.999f);
      oma = 1.f - alpha;
    }
    float s = oma;
    s += __shfl_xor(s, 1);  s += __shfl_xor(s, 2);  s += __shfl_xor(s, 4);
    s += __shfl_xor(s, 8);  s += __shfl_xor(s, 16);
    float ds = __shfl(s, 0) * (1.0f/32.0f);
    if (lane < NHD) ema = ema_new;
    if (lane == 0) ws[WS_DS + c] = ds;
    ds_prev = ds;
  }
}

// ---------------- K3: MFMA — CB, Y_intra, h_contrib ----------------
__global__ __launch_bounds__(256, 2) void k_chunk(
    const float* __restrict__ X, const float* __restrict__ Bm,
    const float* __restrict__ Cm, float* __restrict__ ws,
    float* __restrict__ Y)
{
  __shared__ short Cs[64*136];
  __shared__ short Bs[64*136];
  __shared__ short BsTw[128*72];
  __shared__ short XsT[64*72];
  __shared__ short Es[64*72];
  __shared__ float Acs[CSZ];
  __shared__ float Wl[CSZ];

  const int tile = blockIdx.x;
  const int c  = tile & 63;
  const int bh = tile >> 6;
  const int b = bh >> 4, h = bh & 15;
  const int tid = threadIdx.x;

  const float dsc = ws[WS_DS + c];
  if (tid < CSZ) {
    float sv  = ws[WS_S + tile*CSZ + tid];
    float s63 = ws[WS_S + tile*CSZ + 63];
    Acs[tid] = dsc*sv;
    Wl[tid]  = expf(dsc*(s63 - sv));
  }
  __syncthreads();

  const float* Bbase = Bm + ((size_t)(b*SEQ + c*CSZ)*NHD + h)*ND;
  const float* Cbase = Cm + ((size_t)(b*SEQ + c*CSZ)*NHD + h)*ND;
  const float* Xbase = X  + ((size_t)(b*SEQ + c*CSZ)*NHD + h)*PD;
  #pragma unroll
  for (int qq = 0; qq < 8; ++qq) {
    int lin = qq*256 + tid;
    int t = lin >> 5, n4 = (lin & 31)*4;
    float4 cv = *(const float4*)(Cbase + (size_t)t*(NHD*ND) + n4);
    short4 cs4; cs4.x=f2bf(cv.x); cs4.y=f2bf(cv.y); cs4.z=f2bf(cv.z); cs4.w=f2bf(cv.w);
    *(short4*)&Cs[t*136 + n4] = cs4;
    float4 bv = *(const float4*)(Bbase + (size_t)t*(NHD*ND) + n4);
    short4 bs4; bs4.x=f2bf(bv.x); bs4.y=f2bf(bv.y); bs4.z=f2bf(bv.z); bs4.w=f2bf(bv.w);
    *(short4*)&Bs[t*136 + n4] = bs4;
    float wt = Wl[t];
    BsTw[(n4+0)*72 + t] = f2bf(bv.x*wt);
    BsTw[(n4+1)*72 + t] = f2bf(bv.y*wt);
    BsTw[(n4+2)*72 + t] = f2bf(bv.z*wt);
    BsTw[(n4+3)*72 + t] = f2bf(bv.w*wt);
  }
  #pragma unroll
  for (int qq = 0; qq < 4; ++qq) {
    int lin = qq*256 + tid;
    int t = lin >> 4, p4 = (lin & 15)*4;
    float4 xv = *(const float4*)(Xbase + (size_t)t*(NHD*PD) + p4);
    XsT[(p4+0)*72 + t] = f2bf(xv.x);
    XsT[(p4+1)*72 + t] = f2bf(xv.y);
    XsT[(p4+2)*72 + t] = f2bf(xv.z);
    XsT[(p4+3)*72 + t] = f2bf(xv.w);
  }
  __syncthreads();

  const int w = tid >> 6;
  const int lane = tid & 63;
  const int m = lane & 15, q = lane >> 4;

  // GEMM1: CB[i][j]
  f32x4 acc0 = {0.f,0.f,0.f,0.f}, acc1 = acc0, acc2 = acc0, acc3 = acc0;
  #pragma unroll
  for (int kk = 0; kk < 4; ++kk) {
    bf16x8 af = *(bf16x8*)&Cs[(w*16+m)*136 + kk*32 + q*8];
    bf16x8 b0 = *(bf16x8*)&Bs[( 0+m)*136 + kk*32 + q*8];
    bf16x8 b1 = *(bf16x8*)&Bs[(16+m)*136 + kk*32 + q*8];
    bf16x8 b2 = *(bf16x8*)&Bs[(32+m)*136 + kk*32 + q*8];
    bf16x8 b3 = *(bf16x8*)&Bs[(48+m)*136 + kk*32 + q*8];
    acc0 = __builtin_amdgcn_mfma_f32_16x16x32_bf16(af, b0, acc0, 0,0,0);
    acc1 = __builtin_amdgcn_mfma_f32_16x16x32_bf16(af, b1, acc1, 0,0,0);
    acc2 = __builtin_amdgcn_mfma_f32_16x16x32_bf16(af, b2, acc2, 0,0,0);
    acc3 = __builtin_amdgcn_mfma_f32_16x16x32_bf16(af, b3, acc3, 0,0,0);
  }
  {
    f32x4 accs[4] = {acc0, acc1, acc2, acc3};
    #pragma unroll
    for (int ct = 0; ct < 4; ++ct) {
      int j = ct*16 + m;
      float aj = Acs[j];
      #pragma unroll
      for (int r = 0; r < 4; ++r) {
        int i = w*16 + q*4 + r;
        float v = (i >= j) ? expf(Acs[i]-aj)*accs[ct][r] : 0.f;
        Es[i*72 + j] = f2bf(v);
      }
    }
  }

  // GEMM3: h_contrib[n][p]
  f32x4 h00={0.f,0.f,0.f,0.f}, h01=h00, h02=h00, h03=h00;
  f32x4 h10=h00, h11=h00, h12=h00, h13=h00;
  #pragma unroll
  for (int kk = 0; kk < 2; ++kk) {
    bf16x8 a0 = *(bf16x8*)&BsTw[((2*w+0)*16+m)*72 + kk*32 + q*8];
    bf16x8 a1 = *(bf16x8*)&BsTw[((2*w+1)*16+m)*72 + kk*32 + q*8];
    bf16x8 x0 = *(bf16x8*)&XsT[( 0+m)*72 + kk*32 + q*8];
    bf16x8 x1 = *(bf16x8*)&XsT[(16+m)*72 + kk*32 + q*8];
    bf16x8 x2 = *(bf16x8*)&XsT[(32+m)*72 + kk*32 + q*8];
    bf16x8 x3 = *(bf16x8*)&XsT[(48+m)*72 + kk*32 + q*8];
    h00 = __builtin_amdgcn_mfma_f32_16x16x32_bf16(a0, x0, h00, 0,0,0);
    h01 = __builtin_amdgcn_mfma_f32_16x16x32_bf16(a0, x1, h01, 0,0,0);
    h02 = __builtin_amdgcn_mfma_f32_16x16x32_bf16(a0, x2, h02, 0,0,0);
    h03 = __builtin_amdgcn_mfma_f32_16x16x32_bf16(a0, x3, h03, 0,0,0);
    h10 = __builtin_amdgcn_mfma_f32_16x16x32_bf16(a1, x0, h10, 0,0,0);
    h11 = __builtin_amdgcn_mfma_f32_16x16x32_bf16(a1, x1, h11, 0,0,0);
    h12 = __builtin_amdgcn_mfma_f32_16x16x32_bf16(a1, x2, h12, 0,0,0);
    h13 = __builtin_amdgcn_mfma_f32_16x16x32_bf16(a1, x3, h13, 0,0,0);
  }

  // GEMM2: Y_intra = E @ X (Es rows written by this wave)
  f32x4 y0={0.f,0.f,0.f,0.f}, y1=y0, y2=y0, y3=y0;
  #pragma unroll
  for (int kk = 0; kk < 2; ++kk) {
    bf16x8 ef = *(bf16x8*)&Es[(w*16+m)*72 + kk*32 + q*8];
    bf16x8 x0 = *(bf16x8*)&XsT[( 0+m)*72 + kk*32 + q*8];
    bf16x8 x1 = *(bf16x8*)&XsT[(16+m)*72 + kk*32 + q*8];
    bf16x8 x2 = *(bf16x8*)&XsT[(32+m)*72 + kk*32 + q*8];
    bf16x8 x3 = *(bf16x8*)&XsT[(48+m)*72 + kk*32 + q*8];
    y0 = __builtin_amdgcn_mfma_f32_16x16x32_bf16(ef, x0, y0, 0,0,0);
    y1 = __builtin_amdgcn_mfma_f32_16x16x32_bf16(ef, x1, y1, 0,0,0);
    y2 = __builtin_amdgcn_mfma_f32_16x16x32_bf16(ef, x2, y2, 0,0,0);
    y3 = __builtin_amdgcn_mfma_f32_16x16x32_bf16(ef, x3, y3, 0,0,0);
  }

  {
    float* Ybase = Y + ((size_t)(b*SEQ + c*CSZ)*NHD + h)*PD;
    f32x4 ys[4] = {y0, y1, y2, y3};
    #pragma unroll
    for (int r = 0; r < 4; ++r) {
      int i = w*16 + q*4 + r;
      #pragma unroll
      for (int ct = 0; ct < 4; ++ct)
        Ybase[(size_t)i*(NHD*PD) + ct*16 + m] = ys[ct][r];
    }
  }
  {
    float* hcp = ws + WS_HC + (size_t)tile*(ND*PD);
    f32x4 hs[2][4] = {{h00,h01,h02,h03},{h10,h11,h12,h13}};
    #pragma unroll
    for (int nt = 0; nt < 2; ++nt)
      #pragma unroll
      for (int r = 0; r < 4; ++r) {
        int n = (2*w+nt)*16 + q*4 + r;
        #pragma unroll
        for (int pt = 0; pt < 4; ++pt)
          hcp[n*PD + pt*16 + m] = hs[nt][pt][r];
      }
  }
}

// ---------------- K4: h-state scan (in place, depth-2 prefetch) -------------
__global__ __launch_bounds__(128) void k_scan(float* __restrict__ ws)
{
  __shared__ float dtbl[NCH];
  const int bh = blockIdx.x >> 4, part = blockIdx.x & 15;
  const int tid = threadIdx.x;
  if (tid < NCH) {
    float s63 = ws[WS_S + (bh*NCH + tid)*CSZ + 63];
    dtbl[tid] = expf(ws[WS_DS + tid]*s63);
  }
  __syncthreads();
  float* base = ws + WS_HC + (size_t)bh*(NCH*ND*PD) + part*512 + tid*4;
  float4 h4 = make_float4(0.f, 0.f, 0.f, 0.f);
  float4 v0 = *(float4*)(base);
  float4 v1 = *(float4*)(base + (size_t)(ND*PD));
  #pragma unroll 1
  for (int c = 0; c < NCH; ++c) {
    float4 vn = make_float4(0.f,0.f,0.f,0.f);
    if (c + 2 < NCH) vn = *(float4*)(base + (size_t)(c+2)*(ND*PD));
    *(float4*)(base + (size_t)c*(ND*PD)) = h4;
    float dt = dtbl[c];
    h4.x = dt*h4.x + v0.x;  h4.y = dt*h4.y + v0.y;
    h4.z = dt*h4.z + v0.z;  h4.w = dt*h4.w + v0.w;
    v0 = v1; v1 = vn;
  }
}

// ---------------- K5: MFMA — Y += dfs o (C @ h_prev) ----------------
__global__ __launch_bounds__(256, 4) void k_inter(
    const float* __restrict__ Cm, float* __restrict__ ws,
    float* __restrict__ Y)
{
  __shared__ short Cs[64*136];
  __shared__ short HsT[64*136];
  __shared__ float Dfs[CSZ];

  const int tile = blockIdx.x;
  const int c  = tile & 63;
  const int bh = tile >> 6;
  const int b = bh >> 4, h = bh & 15;
  const int tid = threadIdx.x;

  const float dsc = ws[WS_DS + c];
  if (tid < CSZ) Dfs[tid] = expf(dsc*ws[WS_S + tile*CSZ + tid]);

  const float* Cbase = Cm + ((size_t)(b*SEQ + c*CSZ)*NHD + h)*ND;
  const float* hp = ws + WS_HC + (size_t)tile*(ND*PD);
  #pragma unroll
  for (int qq = 0; qq < 8; ++qq) {
    int lin = qq*256 + tid;
    int t = lin >> 5, n4 = (lin & 31)*4;
    float4 cv = *(const float4*)(Cbase + (size_t)t*(NHD*ND) + n4);
    short4 cs4; cs4.x=f2bf(cv.x); cs4.y=f2bf(cv.y); cs4.z=f2bf(cv.z); cs4.w=f2bf(cv.w);
    *(short4*)&Cs[t*136 + n4] = cs4;
    int p4 = (lin & 15)*4, n = lin >> 4;
    float4 hv = *(const float4*)(hp + (size_t)lin*4);
    HsT[(p4+0)*136 + n] = f2bf(hv.x);
    HsT[(p4+1)*136 + n] = f2bf(hv.y);
    HsT[(p4+2)*136 + n] = f2bf(hv.z);
    HsT[(p4+3)*136 + n] = f2bf(hv.w);
  }
  __syncthreads();

  const int w = tid >> 6;
  const int lane = tid & 63;
  const int m = lane & 15, q = lane >> 4;

  f32x4 a0 = {0.f,0.f,0.f,0.f}, a1 = a0, a2 = a0, a3 = a0;
  #pragma unroll
  for (int kk = 0; kk < 4; ++kk) {
    bf16x8 cf = *(bf16x8*)&Cs[(w*16+m)*136 + kk*32 + q*8];
    bf16x8 hb0 = *(bf16x8*)&HsT[( 0+m)*136 + kk*32 + q*8];
    bf16x8 hb1 = *(bf16x8*)&HsT[(16+m)*136 + kk*32 + q*8];
    bf16x8 hb2 = *(bf16x8*)&HsT[(32+m)*136 + kk*32 + q*8];
    bf16x8 hb3 = *(bf16x8*)&HsT[(48+m)*136 + kk*32 + q*8];
    a0 = __builtin_amdgcn_mfma_f32_16x16x32_bf16(cf, hb0, a0, 0,0,0);
    a1 = __builtin_amdgcn_mfma_f32_16x16x32_bf16(cf, hb1, a1, 0,0,0);
    a2 = __builtin_amdgcn_mfma_f32_16x16x32_bf16(cf, hb2, a2, 0,0,0);
    a3 = __builtin_amdgcn_mfma_f32_16x16x32_bf16(cf, hb3, a3, 0,0,0);
  }

  float* Ybase = Y + ((size_t)(b*SEQ + c*CSZ)*NHD + h)*PD;
  f32x4 as[4] = {a0, a1, a2, a3};
  #pragma unroll
  for (int r = 0; r < 4; ++r) {
    int i = w*16 + q*4 + r;
    float d = Dfs[i];
    #pragma unroll
    for (int ct = 0; ct < 4; ++ct) {
      size_t idx = (size_t)i*(NHD*PD) + ct*16 + m;
      Ybase[idx] += d*as[ct][r];
    }
  }
}

extern "C" void kernel_launch(void* const* d_in, const int* in_sizes, int n_in,
                              void* d_out, int out_size, void* d_ws, size_t ws_size,
                              hipStream_t stream) {
  const float* X    = (const float*)d_in[0];
  const float* A    = (const float*)d_in[1];
  const float* Bm   = (const float*)d_in[2];
  const float* Cm   = (const float*)d_in[3];
  const float* l2ab = (const float*)d_in[4];
  const float* l2b  = (const float*)d_in[5];
  const float* sema = (const float*)d_in[6];
  float* Y  = (float*)d_out;
  float* ws = (float*)d_ws;

  hipLaunchKernelGGL(k_gram,  dim3(NTILES), dim3(256), 0, stream, X, A, Bm, ws);
  hipLaunchKernelGGL(k_gate,  dim3(1),      dim3(64),  0, stream, l2ab, l2b, sema, ws);
  hipLaunchKernelGGL(k_chunk, dim3(NTILES), dim3(256), 0, stream, X, Bm, Cm, ws, Y);
  hipLaunchKernelGGL(k_scan,  dim3(512),    dim3(128), 0, stream, ws);
  hipLaunchKernelGGL(k_inter, dim3(NTILES), dim3(256), 0, stream, Cm, ws, Y);
}